// Round 5
// baseline (231.978 us; speedup 1.0000x reference)
//
#include <hip/hip_runtime.h>
#include <stdint.h>

// Problem constants (fixed by the reference file)
#define T_TOTAL  4194304          // B*K*N = 8*4*131072
#define NEG_IDLE (-100000000.0f)
#define NEG_FILL (-1000.0f)

#define BLOCK  256
#define EPT    8
#define EPB    (BLOCK * EPT)        // 2048 elements per chunk
#define NCHUNK (T_TOTAL / EPB)      // 2048 chunks
// N = 131072 = 64 * 2048 -> each chunk has one uniform (b,k): bk = chunk >> 6

// Workspace layout:
//   [0 .. 16K)      : sums[2048]  u64 packed (surf count low32, air high32)
//   [16K .. 16K+1M) : packed bits, u16 per thread (surf low8 | air<<8)
// K1 fully writes both regions before K2 reads them (stream order), so the
// 0xAA re-poison of d_ws needs no init kernel.

typedef float    f32x4 __attribute__((ext_vector_type(4)));
typedef unsigned u32x4 __attribute__((ext_vector_type(4)));

// 8 consecutive int32 bool elements -> 8-bit mask (jnp bool arrives as int32).
// Nontemporal: mask bytes are read exactly once, keep them out of L2.
__device__ __forceinline__ unsigned decode8_i32(const u32x4* p) {
    const u32x4 a = __builtin_nontemporal_load(p);
    const u32x4 b = __builtin_nontemporal_load(p + 1);
    return (a.x ? 1u : 0u) | (a.y ? 2u : 0u) | (a.z ? 4u : 0u) | (a.w ? 8u : 0u)
         | (b.x ? 16u : 0u) | (b.y ? 32u : 0u) | (b.z ? 64u : 0u) | (b.w ? 128u : 0u);
}

// ---------------------------------------------------------------------------
// Kernel 1: per-chunk mask popcounts + bit-repack (1 barrier)
// ---------------------------------------------------------------------------
__global__ __launch_bounds__(BLOCK) void reduce_pack_kernel(
    const u32x4* __restrict__ ms,
    const u32x4* __restrict__ ma,
    unsigned long long* __restrict__ sums,
    unsigned short* __restrict__ packed)
{
    const int blk  = blockIdx.x;
    const int tid  = threadIdx.x;
    const int lane = tid & 63;
    const int wave = tid >> 6;
    const size_t e = (size_t)blk * EPB + (size_t)tid * EPT;

    const unsigned bits_s = decode8_i32(ms + (e >> 2));
    const unsigned bits_a = decode8_i32(ma + (e >> 2));
    packed[blk * BLOCK + tid] = (unsigned short)(bits_s | (bits_a << 8));

    unsigned long long v =
        ((unsigned long long)(unsigned)__popc(bits_a) << 32) | (unsigned)__popc(bits_s);
    #pragma unroll
    for (int d = 32; d; d >>= 1) v += __shfl_down(v, d, 64);

    __shared__ unsigned long long w[BLOCK / 64];
    if (lane == 0) w[wave] = v;
    __syncthreads();
    if (tid == 0) sums[blk] = w[0] + w[1] + w[2] + w[3];
}

// ---------------------------------------------------------------------------
// Kernel 2: role-split scatter. Grid = 3 * NCHUNK blocks.
//   role 0: rgb (gathers bits_s), role 1: logits_surface (bits_s),
//   role 2: logits_air (bits_a).
// Each block: redundant prefix reduce over sums[] (16 KB, L2-hit) + 32-bit
// wave scan + popcount-derived per-element indices + gather + select +
// nontemporal vectorized stores.
// ---------------------------------------------------------------------------
__global__ __launch_bounds__(BLOCK) void scatter_kernel(
    const float* __restrict__ rgb,
    const float* __restrict__ ls,
    const float* __restrict__ la,
    const unsigned long long* __restrict__ sums,
    const unsigned short* __restrict__ packed,
    const float* __restrict__ idle_states,
    float* __restrict__ out)
{
    const int bid  = blockIdx.x;
    const int role = bid >> 11;            // /NCHUNK: 0=rgb 1=ls 2=la
    const int blk  = bid & (NCHUNK - 1);
    const int tid  = threadIdx.x;
    const int lane = tid & 63;
    const int wave = tid >> 6;
    const size_t base = (size_t)blk * EPB + (size_t)tid * EPT;

    const unsigned pw   = packed[blk * BLOCK + tid];
    const unsigned bits = (role == 2) ? (pw >> 8) : (pw & 0xffu);
    const int c = __popc(bits);

    // ---- block prefix: threads cooperatively reduce sums[0..blk) ----
    // 2048 u64 = 16 KB, L2-resident; thread t covers indices 8t..8t+7.
    unsigned long long acc = 0;
    {
        const ulonglong2* s2 = (const ulonglong2*)sums;
        const int i0 = tid * 8;
        #pragma unroll
        for (int q = 0; q < 4; ++q) {
            const ulonglong2 v = s2[tid * 4 + q];
            const int i = i0 + 2 * q;
            acc += (i     < blk) ? v.x : 0ull;
            acc += (i + 1 < blk) ? v.y : 0ull;
        }
        #pragma unroll
        for (int d = 32; d; d >>= 1) acc += __shfl_down(acc, d, 64);
    }

    // ---- 32-bit wave inclusive scan of per-thread count ----
    int incl = c;
    #pragma unroll
    for (int d = 1; d < 64; d <<= 1) {
        const int t = __shfl_up(incl, d, 64);
        if (lane >= d) incl += t;
    }
    int excl = incl - c;

    __shared__ int wtot[BLOCK / 64];
    __shared__ unsigned long long wpre[BLOCK / 64];
    if (lane == 63) wtot[wave] = incl;
    if (lane == 0)  wpre[wave] = acc;
    __syncthreads();
    #pragma unroll
    for (int w = 0; w < BLOCK / 64; ++w)
        if (w < wave) excl += wtot[w];
    const unsigned long long pre = wpre[0] + wpre[1] + wpre[2] + wpre[3];
    const int pre32 = (role == 2) ? (int)(pre >> 32) : (int)(pre & 0xffffffffull);
    const int idx0  = pre32 + excl;

    // per-element indices: branch-free, no serial dependency chain
    int idx[EPT];
    #pragma unroll
    for (int j = 0; j < EPT; ++j)
        idx[j] = idx0 + __popc(bits & ((1u << j) - 1u));

    const float idle      = idle_states[blk >> 6];   // uniform per block
    const float scale     = 1.0f - idle;
    const float idle_term = idle * NEG_IDLE;

    if (role == 0) {
        // ---- rgb: gather 8 triples, scale/select, 96 B NT store ----
        float r[3 * EPT];
        #pragma unroll
        for (int j = 0; j < EPT; ++j) {
            const float* rp = rgb + (size_t)idx[j] * 3;   // always in-bounds
            r[3 * j + 0] = rp[0];
            r[3 * j + 1] = rp[1];
            r[3 * j + 2] = rp[2];
        }
        #pragma unroll
        for (int j = 0; j < EPT; ++j) {
            const bool bs = (bits >> j) & 1u;
            r[3 * j + 0] = bs ? r[3 * j + 0] * scale : 0.0f;
            r[3 * j + 1] = bs ? r[3 * j + 1] * scale : 0.0f;
            r[3 * j + 2] = bs ? r[3 * j + 2] * scale : 0.0f;
        }
        f32x4* dst = (f32x4*)(out + base * 3);
        #pragma unroll
        for (int j = 0; j < 6; ++j) {
            const f32x4 v = { r[4 * j + 0], r[4 * j + 1], r[4 * j + 2], r[4 * j + 3] };
            __builtin_nontemporal_store(v, dst + j);
        }
    } else {
        // ---- logits: gather 8, scale/select, 32 B NT store ----
        const float* src = (role == 1) ? ls : la;
        float v[EPT];
        #pragma unroll
        for (int j = 0; j < EPT; ++j) v[j] = src[idx[j]];
        #pragma unroll
        for (int j = 0; j < EPT; ++j) {
            const bool b = (bits >> j) & 1u;
            v[j] = b ? (v[j] * scale + idle_term) : NEG_FILL;
        }
        float* obase = out + (size_t)(2 + role) * T_TOTAL + base;  // 3T or 4T
        const f32x4 v0 = { v[0], v[1], v[2], v[3] };
        const f32x4 v1 = { v[4], v[5], v[6], v[7] };
        __builtin_nontemporal_store(v0, (f32x4*)obase);
        __builtin_nontemporal_store(v1, (f32x4*)obase + 1);
    }
}

// ---------------------------------------------------------------------------
extern "C" void kernel_launch(void* const* d_in, const int* in_sizes, int n_in,
                              void* d_out, int out_size, void* d_ws, size_t ws_size,
                              hipStream_t stream) {
    const float* rgb  = (const float*)d_in[0];
    const float* ls   = (const float*)d_in[1];
    const float* la   = (const float*)d_in[2];
    const u32x4* ms   = (const u32x4*)d_in[3];   // jnp bool -> int32 on device
    const u32x4* ma   = (const u32x4*)d_in[4];
    const float* idle = (const float*)d_in[5];
    float* out = (float*)d_out;

    unsigned long long* sums   = (unsigned long long*)d_ws;
    unsigned short*     packed =
        (unsigned short*)((uint8_t*)d_ws + NCHUNK * sizeof(unsigned long long));

    reduce_pack_kernel<<<NCHUNK, BLOCK, 0, stream>>>(ms, ma, sums, packed);
    scatter_kernel<<<3 * NCHUNK, BLOCK, 0, stream>>>(rgb, ls, la, sums, packed,
                                                     idle, out);
}

// Round 6
// 197.874 us; speedup vs baseline: 1.1724x; 1.1724x over previous
//
#include <hip/hip_runtime.h>
#include <stdint.h>

// Problem constants (fixed by the reference file)
#define T_TOTAL  4194304          // B*K*N = 8*4*131072
#define NEG_IDLE (-100000000.0f)
#define NEG_FILL (-1000.0f)

#define BLOCK  256
#define EPT    8
#define EPB    (BLOCK * EPT)        // 2048 elements per block
#define NCHUNK (T_TOTAL / EPB)      // 2048 blocks
// N = 131072 = 64 * 2048 -> each block has one uniform (b,k): bk = blk >> 6

// Workspace layout:
//   [0 .. 16K)      : sums[2048]  u64 packed (surf count low32, air high32)
//   [16K .. 16K+1M) : packed bits, u16 per thread (surf low8 | air<<8)
// K1 fully writes both regions before K2 reads them (stream order), so the
// 0xAA re-poison of d_ws needs no init kernel.

// 8 consecutive int32 bool elements -> 8-bit mask (jnp bool arrives as int32)
__device__ __forceinline__ unsigned decode8_i32(const uint4* p) {
    const uint4 a = p[0], b = p[1];
    return (a.x ? 1u : 0u) | (a.y ? 2u : 0u) | (a.z ? 4u : 0u) | (a.w ? 8u : 0u)
         | (b.x ? 16u : 0u) | (b.y ? 32u : 0u) | (b.z ? 64u : 0u) | (b.w ? 128u : 0u);
}

// ---------------------------------------------------------------------------
// Kernel 1: per-block mask popcounts + bit-repack (1 barrier)
// ---------------------------------------------------------------------------
__global__ __launch_bounds__(BLOCK) void reduce_pack_kernel(
    const uint4* __restrict__ ms,
    const uint4* __restrict__ ma,
    unsigned long long* __restrict__ sums,
    unsigned short* __restrict__ packed)
{
    const int blk  = blockIdx.x;
    const int tid  = threadIdx.x;
    const int lane = tid & 63;
    const int wave = tid >> 6;
    const size_t e = (size_t)blk * EPB + (size_t)tid * EPT;

    const unsigned bits_s = decode8_i32(ms + (e >> 2));
    const unsigned bits_a = decode8_i32(ma + (e >> 2));
    packed[blk * BLOCK + tid] = (unsigned short)(bits_s | (bits_a << 8));

    unsigned long long v =
        ((unsigned long long)(unsigned)__popc(bits_a) << 32) | (unsigned)__popc(bits_s);
    #pragma unroll
    for (int d = 32; d; d >>= 1) v += __shfl_down(v, d, 64);

    __shared__ unsigned long long w[BLOCK / 64];
    if (lane == 0) w[wave] = v;
    __syncthreads();
    if (tid == 0) sums[blk] = w[0] + w[1] + w[2] + w[3];
}

// ---------------------------------------------------------------------------
// Kernel 2: scatter with LDS-staged gathers.
// Monotone indices => each block's gather sources are the contiguous ranges
// rgb[3*S0..3*S1), ls[S0..S1), la[A0..A1). Stream them into LDS with
// coalesced loads, then read fragments from LDS via the BLOCK-LOCAL scan
// (global prefix only needed for the staging base). Plain (cached) stores:
// L2 merges the 16B chunks into full lines (NT stores caused 2x write amp).
// ---------------------------------------------------------------------------
__global__ __launch_bounds__(BLOCK) void scatter_kernel(
    const float* __restrict__ rgb,
    const float* __restrict__ ls,
    const float* __restrict__ la,
    const unsigned long long* __restrict__ sums,
    const unsigned short* __restrict__ packed,
    const float* __restrict__ idle_states,
    float* __restrict__ out)
{
    __shared__ float lds_rgb[3 * EPB];   // 24 KB (worst case: all masked)
    __shared__ float lds_ls[EPB];        //  8 KB
    __shared__ float lds_la[EPB];        //  8 KB

    const int blk  = blockIdx.x;
    const int tid  = threadIdx.x;
    const int lane = tid & 63;
    const int wave = tid >> 6;
    const size_t base = (size_t)blk * EPB + (size_t)tid * EPT;

    // ---- masks ----
    const unsigned p = packed[blk * BLOCK + tid];
    const unsigned bits_s = p & 0xffu;
    const unsigned bits_a = p >> 8;

    // ---- block prefix: threads cooperatively reduce sums[0..blk) ----
    // 2048 u64 = 16 KB, L2-resident; thread t covers indices 8t..8t+7.
    unsigned long long acc = 0;
    {
        const ulonglong2* s2 = (const ulonglong2*)sums;
        const int i0 = tid * 8;
        #pragma unroll
        for (int q = 0; q < 4; ++q) {
            const ulonglong2 v = s2[tid * 4 + q];
            const int i = i0 + 2 * q;
            acc += (i     < blk) ? v.x : 0ull;
            acc += (i + 1 < blk) ? v.y : 0ull;
        }
        #pragma unroll
        for (int d = 32; d; d >>= 1) acc += __shfl_down(acc, d, 64);
    }

    // ---- wave-level inclusive scan of packed (air<<32 | surf) counts ----
    const unsigned long long pk =
        ((unsigned long long)(unsigned)__popc(bits_a) << 32) | (unsigned)__popc(bits_s);
    unsigned long long incl = pk;
    #pragma unroll
    for (int d = 1; d < 64; d <<= 1) {
        unsigned long long t = __shfl_up(incl, d, 64);
        if (lane >= d) incl += t;
    }
    unsigned long long excl = incl - pk;

    __shared__ unsigned long long wtot[BLOCK / 64];
    __shared__ unsigned long long wpre[BLOCK / 64];
    if (lane == 63) wtot[wave] = incl;
    if (lane == 0)  wpre[wave] = acc;
    __syncthreads();
    #pragma unroll
    for (int w = 0; w < BLOCK / 64; ++w)
        if (w < wave) excl += wtot[w];
    const unsigned long long pre = wpre[0] + wpre[1] + wpre[2] + wpre[3];

    const int S0 = (int)(pre & 0xffffffffULL);   // global surf base of block
    const int A0 = (int)(pre >> 32);             // global air base of block
    const unsigned long long tot = wtot[0] + wtot[1] + wtot[2] + wtot[3];
    const int cs_tot = (int)(tot & 0xffffffffULL);   // block surf count
    const int ca_tot = (int)(tot >> 32);             // block air count

    // ---- cooperative coalesced staging of the contiguous gather ranges ----
    for (int i = tid; i < 3 * cs_tot; i += BLOCK)
        lds_rgb[i] = rgb[(size_t)3 * S0 + i];
    for (int i = tid; i < cs_tot; i += BLOCK)
        lds_ls[i] = ls[S0 + i];
    for (int i = tid; i < ca_tot; i += BLOCK)
        lds_la[i] = la[A0 + i];
    __syncthreads();

    // ---- block-local per-element indices (branch-free, popcount-derived) ----
    const int ls0 = (int)(excl & 0xffffffffULL);
    const int la0 = (int)(excl >> 32);
    int is_[EPT], ia_[EPT];
    #pragma unroll
    for (int j = 0; j < EPT; ++j) {
        is_[j] = ls0 + __popc(bits_s & ((1u << j) - 1u));
        ia_[j] = la0 + __popc(bits_a & ((1u << j) - 1u));
    }

    // ---- read fragments from LDS ----
    float r[3 * EPT], sv[EPT], av[EPT];
    #pragma unroll
    for (int j = 0; j < EPT; ++j) {
        r[3 * j + 0] = lds_rgb[3 * is_[j] + 0];
        r[3 * j + 1] = lds_rgb[3 * is_[j] + 1];
        r[3 * j + 2] = lds_rgb[3 * is_[j] + 2];
        sv[j] = lds_ls[is_[j]];
        av[j] = lds_la[ia_[j]];
    }

    // ---- select/scale ----
    const float idle      = idle_states[blk >> 6];   // uniform per block
    const float scale     = 1.0f - idle;
    const float idle_term = idle * NEG_IDLE;
    #pragma unroll
    for (int j = 0; j < EPT; ++j) {
        const bool bs = (bits_s >> j) & 1u;
        const bool ba = (bits_a >> j) & 1u;
        r[3 * j + 0] = bs ? r[3 * j + 0] * scale : 0.0f;
        r[3 * j + 1] = bs ? r[3 * j + 1] * scale : 0.0f;
        r[3 * j + 2] = bs ? r[3 * j + 2] * scale : 0.0f;
        sv[j] = bs ? (sv[j] * scale + idle_term) : NEG_FILL;
        av[j] = ba ? (av[j] * scale + idle_term) : NEG_FILL;
    }

    // ---- vectorized stores (plain/cached: L2 merges into full lines) ----
    float4* prgb = (float4*)(out + base * 3);                    // 96 B/thread
    #pragma unroll
    for (int j = 0; j < 6; ++j) prgb[j] = ((const float4*)r)[j];

    float4* pls = (float4*)(out + (size_t)3 * T_TOTAL + base);   // 32 B/thread
    pls[0] = ((const float4*)sv)[0];
    pls[1] = ((const float4*)sv)[1];

    float4* pla = (float4*)(out + (size_t)4 * T_TOTAL + base);
    pla[0] = ((const float4*)av)[0];
    pla[1] = ((const float4*)av)[1];
}

// ---------------------------------------------------------------------------
extern "C" void kernel_launch(void* const* d_in, const int* in_sizes, int n_in,
                              void* d_out, int out_size, void* d_ws, size_t ws_size,
                              hipStream_t stream) {
    const float* rgb  = (const float*)d_in[0];
    const float* ls   = (const float*)d_in[1];
    const float* la   = (const float*)d_in[2];
    const uint4* ms   = (const uint4*)d_in[3];   // jnp bool -> int32 on device
    const uint4* ma   = (const uint4*)d_in[4];
    const float* idle = (const float*)d_in[5];
    float* out = (float*)d_out;

    unsigned long long* sums   = (unsigned long long*)d_ws;
    unsigned short*     packed =
        (unsigned short*)((uint8_t*)d_ws + NCHUNK * sizeof(unsigned long long));

    reduce_pack_kernel<<<NCHUNK, BLOCK, 0, stream>>>(ms, ma, sums, packed);
    scatter_kernel<<<NCHUNK, BLOCK, 0, stream>>>(rgb, ls, la, sums, packed,
                                                 idle, out);
}

// Round 7
// 193.429 us; speedup vs baseline: 1.1993x; 1.0230x over previous
//
#include <hip/hip_runtime.h>
#include <stdint.h>

// Problem constants (fixed by the reference file)
#define T_TOTAL  4194304          // B*K*N = 8*4*131072
#define NEG_IDLE (-100000000.0f)
#define NEG_FILL (-1000.0f)

#define BLOCK  256
#define EPT    8
#define EPB    (BLOCK * EPT)        // 2048 elements per chunk
#define NCHUNK (T_TOTAL / EPB)      // 2048 chunks
// N = 131072 = 64 * 2048 -> each chunk has one uniform (b,k): bk = chunk >> 6

// Workspace layout:
//   [0 .. 16K)      : sums[2048]  u64 packed (surf count low32, air high32)
//   [16K .. 16K+1M) : packed bits, u16 per thread (surf low8 | air<<8)
// K1 fully writes both regions before K2 reads them (stream order), so the
// 0xAA re-poison of d_ws needs no init kernel.

typedef unsigned u32x4 __attribute__((ext_vector_type(4)));

// 8 consecutive int32 bool elements -> 8-bit mask (jnp bool arrives as int32).
// Nontemporal LOADS only (read-once stream; keep L2 for gather reuse).
__device__ __forceinline__ unsigned decode8_i32(const u32x4* p) {
    const u32x4 a = __builtin_nontemporal_load(p);
    const u32x4 b = __builtin_nontemporal_load(p + 1);
    return (a.x ? 1u : 0u) | (a.y ? 2u : 0u) | (a.z ? 4u : 0u) | (a.w ? 8u : 0u)
         | (b.x ? 16u : 0u) | (b.y ? 32u : 0u) | (b.z ? 64u : 0u) | (b.w ? 128u : 0u);
}

// ---------------------------------------------------------------------------
// Kernel 1: per-chunk mask popcounts + bit-repack (1 barrier)
// ---------------------------------------------------------------------------
__global__ __launch_bounds__(BLOCK) void reduce_pack_kernel(
    const u32x4* __restrict__ ms,
    const u32x4* __restrict__ ma,
    unsigned long long* __restrict__ sums,
    unsigned short* __restrict__ packed)
{
    const int blk  = blockIdx.x;
    const int tid  = threadIdx.x;
    const int lane = tid & 63;
    const int wave = tid >> 6;
    const size_t e = (size_t)blk * EPB + (size_t)tid * EPT;

    const unsigned bits_s = decode8_i32(ms + (e >> 2));
    const unsigned bits_a = decode8_i32(ma + (e >> 2));
    packed[blk * BLOCK + tid] = (unsigned short)(bits_s | (bits_a << 8));

    unsigned long long v =
        ((unsigned long long)(unsigned)__popc(bits_a) << 32) | (unsigned)__popc(bits_s);
    #pragma unroll
    for (int d = 32; d; d >>= 1) v += __shfl_down(v, d, 64);

    __shared__ unsigned long long w[BLOCK / 64];
    if (lane == 0) w[wave] = v;
    __syncthreads();
    if (tid == 0) sums[blk] = w[0] + w[1] + w[2] + w[3];
}

// ---------------------------------------------------------------------------
// Kernel 2: role-split scatter. Grid = 3 * NCHUNK blocks.
//   role 0: rgb (bits_s), role 1: logits_surface (bits_s), role 2: la (bits_a)
// Direct gathers (L3 absorbs re-reads; LDS staging disproved in r6) +
// PLAIN cached stores (NT stores caused 2x write amplification in r5 —
// L2 write-back merges the 16B chunks into full lines).
// ---------------------------------------------------------------------------
__global__ __launch_bounds__(BLOCK) void scatter_kernel(
    const float* __restrict__ rgb,
    const float* __restrict__ ls,
    const float* __restrict__ la,
    const unsigned long long* __restrict__ sums,
    const unsigned short* __restrict__ packed,
    const float* __restrict__ idle_states,
    float* __restrict__ out)
{
    const int bid  = blockIdx.x;
    const int role = bid >> 11;            // /NCHUNK: 0=rgb 1=ls 2=la
    const int blk  = bid & (NCHUNK - 1);
    const int tid  = threadIdx.x;
    const int lane = tid & 63;
    const int wave = tid >> 6;
    const size_t base = (size_t)blk * EPB + (size_t)tid * EPT;

    const unsigned pw   = packed[blk * BLOCK + tid];
    const unsigned bits = (role == 2) ? (pw >> 8) : (pw & 0xffu);
    const int c = __popc(bits);

    // ---- block prefix: threads cooperatively reduce sums[0..blk) ----
    // 2048 u64 = 16 KB, L2-resident; thread t covers indices 8t..8t+7.
    unsigned long long acc = 0;
    {
        const ulonglong2* s2 = (const ulonglong2*)sums;
        const int i0 = tid * 8;
        #pragma unroll
        for (int q = 0; q < 4; ++q) {
            const ulonglong2 v = s2[tid * 4 + q];
            const int i = i0 + 2 * q;
            acc += (i     < blk) ? v.x : 0ull;
            acc += (i + 1 < blk) ? v.y : 0ull;
        }
        #pragma unroll
        for (int d = 32; d; d >>= 1) acc += __shfl_down(acc, d, 64);
    }

    // ---- 32-bit wave inclusive scan of per-thread count ----
    int incl = c;
    #pragma unroll
    for (int d = 1; d < 64; d <<= 1) {
        const int t = __shfl_up(incl, d, 64);
        if (lane >= d) incl += t;
    }
    int excl = incl - c;

    __shared__ int wtot[BLOCK / 64];
    __shared__ unsigned long long wpre[BLOCK / 64];
    if (lane == 63) wtot[wave] = incl;
    if (lane == 0)  wpre[wave] = acc;
    __syncthreads();
    #pragma unroll
    for (int w = 0; w < BLOCK / 64; ++w)
        if (w < wave) excl += wtot[w];
    const unsigned long long pre = wpre[0] + wpre[1] + wpre[2] + wpre[3];
    const int pre32 = (role == 2) ? (int)(pre >> 32) : (int)(pre & 0xffffffffull);
    const int idx0  = pre32 + excl;

    // per-element indices: branch-free, no serial dependency chain
    int idx[EPT];
    #pragma unroll
    for (int j = 0; j < EPT; ++j)
        idx[j] = idx0 + __popc(bits & ((1u << j) - 1u));

    const float idle      = idle_states[blk >> 6];   // uniform per block
    const float scale     = 1.0f - idle;
    const float idle_term = idle * NEG_IDLE;

    if (role == 0) {
        // ---- rgb: gather 8 triples, scale/select, 96 B plain store ----
        float r[3 * EPT];
        #pragma unroll
        for (int j = 0; j < EPT; ++j) {
            const float* rp = rgb + (size_t)idx[j] * 3;   // always in-bounds
            r[3 * j + 0] = rp[0];
            r[3 * j + 1] = rp[1];
            r[3 * j + 2] = rp[2];
        }
        #pragma unroll
        for (int j = 0; j < EPT; ++j) {
            const bool bs = (bits >> j) & 1u;
            r[3 * j + 0] = bs ? r[3 * j + 0] * scale : 0.0f;
            r[3 * j + 1] = bs ? r[3 * j + 1] * scale : 0.0f;
            r[3 * j + 2] = bs ? r[3 * j + 2] * scale : 0.0f;
        }
        float4* dst = (float4*)(out + base * 3);
        #pragma unroll
        for (int j = 0; j < 6; ++j) dst[j] = ((const float4*)r)[j];
    } else {
        // ---- logits: gather 8, scale/select, 32 B plain store ----
        const float* src = (role == 1) ? ls : la;
        float v[EPT];
        #pragma unroll
        for (int j = 0; j < EPT; ++j) v[j] = src[idx[j]];
        #pragma unroll
        for (int j = 0; j < EPT; ++j) {
            const bool b = (bits >> j) & 1u;
            v[j] = b ? (v[j] * scale + idle_term) : NEG_FILL;
        }
        float4* obase = (float4*)(out + (size_t)(2 + role) * T_TOTAL + base);
        obase[0] = ((const float4*)v)[0];
        obase[1] = ((const float4*)v)[1];
    }
}

// ---------------------------------------------------------------------------
extern "C" void kernel_launch(void* const* d_in, const int* in_sizes, int n_in,
                              void* d_out, int out_size, void* d_ws, size_t ws_size,
                              hipStream_t stream) {
    const float* rgb  = (const float*)d_in[0];
    const float* ls   = (const float*)d_in[1];
    const float* la   = (const float*)d_in[2];
    const u32x4* ms   = (const u32x4*)d_in[3];   // jnp bool -> int32 on device
    const u32x4* ma   = (const u32x4*)d_in[4];
    const float* idle = (const float*)d_in[5];
    float* out = (float*)d_out;

    unsigned long long* sums   = (unsigned long long*)d_ws;
    unsigned short*     packed =
        (unsigned short*)((uint8_t*)d_ws + NCHUNK * sizeof(unsigned long long));

    reduce_pack_kernel<<<NCHUNK, BLOCK, 0, stream>>>(ms, ma, sums, packed);
    scatter_kernel<<<3 * NCHUNK, BLOCK, 0, stream>>>(rgb, ls, la, sums, packed,
                                                     idle, out);
}